// Round 9
// baseline (353.185 us; speedup 1.0000x reference)
//
#include <hip/hip_runtime.h>

#define EPSF 1e-5f
#define DECAYF 0.99f
#define KCODES 2048
#define DIM 256

typedef _Float16 f16;
typedef f16 f16x8 __attribute__((ext_vector_type(8)));
typedef float f32x4 __attribute__((ext_vector_type(4)));

#define MFMA16(A, B, C) __builtin_amdgcn_mfma_f32_16x16x32_f16(A, B, C, 0, 0, 0)

#define OFF_AH 0
#define OFF_AL 16384
#define OFF_BH 32768
#define OFF_BL 49152

__device__ __forceinline__ void gload_lds16(const void* g, void* l) {
    __builtin_amdgcn_global_load_lds(
        (const __attribute__((address_space(1))) void*)g,
        (__attribute__((address_space(3))) void*)l, 16, 0, 0);
}

// ---------------------------------------------------------------------------
// fused split_x + prep_embed; also accumulates max_x2 and min_e2 stats.
// blocks [0, nsplit): xh=(f16)x, xl=(f16)(x-xh) (8 rows of x per block)
// blocks [nsplit, nsplit+K): embed, e2, eh/el split
// ---------------------------------------------------------------------------
__global__ __launch_bounds__(256) void split_prep_kernel(
    const float* __restrict__ x, f16* __restrict__ xh, f16* __restrict__ xl, int nsplit,
    const float* __restrict__ embed_sum, const float* __restrict__ usage,
    float* __restrict__ embed, f16* __restrict__ eh, f16* __restrict__ el,
    float* __restrict__ e2, unsigned* __restrict__ maxx2_u, unsigned* __restrict__ mine2_u)
{
    if ((int)blockIdx.x < nsplit) {
        int i = blockIdx.x * 256 + threadIdx.x;
        f32x4 v0 = ((const f32x4*)x)[2 * i];
        f32x4 v1 = ((const f32x4*)x)[2 * i + 1];
        f16x8 h, l;
        float p = 0.f;
        #pragma unroll
        for (int t = 0; t < 4; ++t) {
            f16 h0 = (f16)v0[t]; h[t] = h0; l[t] = (f16)(v0[t] - (float)h0);
            f16 h1 = (f16)v1[t]; h[t + 4] = h1; l[t + 4] = (f16)(v1[t] - (float)h1);
            p += v0[t] * v0[t] + v1[t] * v1[t];
        }
        ((f16x8*)xh)[i] = h;
        ((f16x8*)xl)[i] = l;
        // per-row x2: 32 consecutive lanes cover one row (8 elems each)
        #pragma unroll
        for (int m = 1; m <= 16; m <<= 1) p += __shfl_xor(p, m, 64);
        float q = fmaxf(p, __shfl_xor(p, 32, 64));   // wave max of its 2 row-sums
        __shared__ float wmax[4];
        if ((threadIdx.x & 63) == 0) wmax[threadIdx.x >> 6] = q;
        __syncthreads();
        if (threadIdx.x == 0) {
            float bm = fmaxf(fmaxf(wmax[0], wmax[1]), fmaxf(wmax[2], wmax[3]));
            atomicMax(maxx2_u, __float_as_uint(bm));
        }
    } else {
        int k = blockIdx.x - nsplit;
        int d = threadIdx.x;
        float inv = 1.0f / fmaxf(usage[k], EPSF);
        float e = embed_sum[k * DIM + d] * inv;
        embed[k * DIM + d] = e;
        float ec = fminf(fmaxf(e, -65000.0f), 65000.0f);
        f16 h = (f16)ec;
        f16 l = (f16)(ec - (float)h);
        eh[k * DIM + d] = h;
        el[k * DIM + d] = l;
        float sq = e * e;
        #pragma unroll
        for (int off = 32; off > 0; off >>= 1) sq += __shfl_down(sq, off, 64);
        __shared__ float ws[4];
        if ((threadIdx.x & 63) == 0) ws[threadIdx.x >> 6] = sq;
        __syncthreads();
        if (threadIdx.x == 0) {
            float s = ws[0] + ws[1] + ws[2] + ws[3];
            e2[k] = s;
            atomicMin(mine2_u, __float_as_uint(s));
        }
    }
}

// ---------------------------------------------------------------------------
// compactA: exact prune threshold + STABLE compaction plan (1 block).
// Winner bound: ||e_k|| <= 2*max||x|| + min||e|| (else provably beaten by
// the min-norm code). Stable scan keeps compact order monotone in k, so
// first-index tie-break is preserved through the remap.
// ---------------------------------------------------------------------------
__global__ __launch_bounds__(256) void compactA_kernel(
    const float* __restrict__ e2, const unsigned* __restrict__ maxx2_u,
    const unsigned* __restrict__ mine2_u, int* __restrict__ cpos,
    float* __restrict__ ce2, int* __restrict__ cmap, int* __restrict__ meta)
{
    __shared__ int ps[256];
    const int t = threadIdx.x;
    const float T0 = 2.0f * sqrtf(__uint_as_float(*maxx2_u)) + sqrtf(__uint_as_float(*mine2_u));
    const float T = T0 * T0 * 1.0002f + 1.0f;
    int flag[8], pre[8], s = 0;
    float ev[8];
    #pragma unroll
    for (int j = 0; j < 8; ++j) {
        ev[j] = e2[t * 8 + j];
        flag[j] = (ev[j] <= T) ? 1 : 0;
        pre[j] = s; s += flag[j];
    }
    ps[t] = s;
    __syncthreads();
    for (int off = 1; off < 256; off <<= 1) {
        int v = (t >= off) ? ps[t - off] : 0;
        __syncthreads();
        ps[t] += v;
        __syncthreads();
    }
    const int ex = (t > 0) ? ps[t - 1] : 0;
    const int kp = ps[255];
    #pragma unroll
    for (int j = 0; j < 8; ++j) {
        const int k = t * 8 + j;
        if (flag[j]) {
            const int p = ex + pre[j];
            cpos[k] = p;
            ce2[p] = ev[j];
            cmap[p] = k;
        } else cpos[k] = -1;
    }
    // pad tail of ce2/cmap to full 2048 with never-winning sentinels
    for (int j = t; j < KCODES; j += 256)
        if (j >= kp) { ce2[j] = 3.4e38f; cmap[j] = 0; }
    if (t == 0) { meta[0] = kp; meta[1] = (kp + 255) & ~255; }
}

// ---------------------------------------------------------------------------
// compactB: gather flagged eh/el rows into ceh/cel; zero the pad rows.
// ---------------------------------------------------------------------------
__global__ __launch_bounds__(256) void compactB_kernel(
    const f16* __restrict__ eh, const f16* __restrict__ el, const int* __restrict__ cpos,
    const int* __restrict__ meta, f16* __restrict__ ceh, f16* __restrict__ cel)
{
    const int b = blockIdx.x, t = threadIdx.x;
    if (b < KCODES) {
        const int p = cpos[b];
        if (p >= 0) {
            ceh[p * DIM + t] = eh[b * DIM + t];
            cel[p * DIM + t] = el[b * DIM + t];
        }
    } else {
        const int slot = meta[0] + (b - KCODES);
        if (slot < meta[1]) {
            ceh[slot * DIM + t] = (f16)0.f;
            cel[slot * DIM + t] = (f16)0.f;
        }
    }
}

// ---------------------------------------------------------------------------
// argmin: round-7 structure (proven 196us @ 8 tiles), runtime tile count
// over the COMPACTED codebook. BM=BN=256, 8 waves (4Mx2N, wave 64x128),
// one s_barrier per 32-d chunk, compiler-interleaved reads+MFMA,
// XOR-swizzled LDS (conflict-free), early staging into parity buffer.
// Winner compact index remapped through cmap (stable -> tie-break exact).
// ---------------------------------------------------------------------------
__global__ __launch_bounds__(512, 2) void argmin_kernel(
    const f16* __restrict__ xh, const f16* __restrict__ xl,
    const f16* __restrict__ ceh, const f16* __restrict__ cel,
    const float* __restrict__ ce2, const int* __restrict__ cmap,
    const int* __restrict__ meta, int* __restrict__ flat_ind, int* __restrict__ cnt)
{
    __shared__ __align__(1024) char lds[2 * 65536 + 8192];
    float* e2s = (float*)(lds + 131072);

    const int ncc = meta[1] >> 5;   // 8 chunks per 256-code tile
    const int tid  = threadIdx.x;
    const int w    = tid >> 6, lane = tid & 63;
    const int l15  = lane & 15, l4 = lane >> 4;
    const int wm   = w >> 1, wn = w & 1;
    const int row0 = blockIdx.x * 256;
    const int gsw  = (lane & 3) ^ ((lane >> 3) & 3);
    const int lq   = lane >> 2;
    const int rslot = (l4 ^ ((l15 >> 1) & 3)) * 16;

    f32x4 acc[4][8];
    float best[16];
    int   bidx[16];
    #pragma unroll
    for (int t = 0; t < 16; ++t) { best[t] = 3.4e38f; bidx[t] = 0; }

    auto stageU = [&](const f16* rowbase, int koff, char* unit) {
        #pragma unroll
        for (int q = 0; q < 2; ++q) {
            const int r = w * 32 + q * 16 + lq;
            gload_lds16(rowbase + (size_t)r * DIM + koff + gsw * 8,
                        unit + w * 2048 + q * 1024 + lane * 16);
        }
    };

    ((f32x4*)e2s)[tid] = ((const f32x4*)ce2)[tid];
    stageU(xh + (size_t)row0 * DIM, 0, lds + OFF_AH);
    stageU(xl + (size_t)row0 * DIM, 0, lds + OFF_AL);
    stageU(ceh, 0, lds + OFF_BH);
    stageU(cel, 0, lds + OFF_BL);

    for (int cc = 0; cc < ncc; ++cc) {
        char* buf  = lds + (cc & 1) * 65536;
        char* nbuf = lds + ((cc + 1) & 1) * 65536;
        const int ct = cc >> 3, sd = cc & 7;
        const int nn = cc + 1;
        const int nct = nn >> 3, nsd = nn & 7;
        const bool more = (nn < ncc);

        if (sd == 0) {
            #pragma unroll
            for (int i = 0; i < 4; ++i)
                #pragma unroll
                for (int j = 0; j < 8; ++j)
                    acc[i][j] = (f32x4){0.f, 0.f, 0.f, 0.f};
        }

        asm volatile("s_waitcnt vmcnt(0)" ::: "memory");
        __builtin_amdgcn_s_barrier();
        __builtin_amdgcn_sched_barrier(0);

        if (more) {
            stageU(xh + (size_t)row0 * DIM, nsd * 32, nbuf + OFF_AH);
            stageU(xl + (size_t)row0 * DIM, nsd * 32, nbuf + OFF_AL);
            stageU(ceh + (size_t)(nct * 256) * DIM, nsd * 32, nbuf + OFF_BH);
            stageU(cel + (size_t)(nct * 256) * DIM, nsd * 32, nbuf + OFF_BL);
        }

        f16x8 ah[4], al[4], bh[8], bl[8];
        #pragma unroll
        for (int i = 0; i < 4; ++i)
            ah[i] = *(const f16x8*)(buf + OFF_AH + (wm * 64 + i * 16 + l15) * 64 + rslot);
        #pragma unroll
        for (int j = 0; j < 8; ++j)
            bh[j] = *(const f16x8*)(buf + OFF_BH + (wn * 128 + j * 16 + l15) * 64 + rslot);
        #pragma unroll
        for (int i = 0; i < 4; ++i)
            al[i] = *(const f16x8*)(buf + OFF_AL + (wm * 64 + i * 16 + l15) * 64 + rslot);

        #pragma unroll
        for (int i = 0; i < 4; ++i)
            #pragma unroll
            for (int j = 0; j < 8; ++j)
                acc[i][j] = MFMA16(ah[i], bh[j], acc[i][j]);
        #pragma unroll
        for (int i = 0; i < 4; ++i)
            #pragma unroll
            for (int j = 0; j < 8; ++j)
                acc[i][j] = MFMA16(al[i], bh[j], acc[i][j]);

        #pragma unroll
        for (int j = 0; j < 8; ++j)
            bl[j] = *(const f16x8*)(buf + OFF_BL + (wn * 128 + j * 16 + l15) * 64 + rslot);
        #pragma unroll
        for (int i = 0; i < 4; ++i)
            #pragma unroll
            for (int j = 0; j < 8; ++j)
                acc[i][j] = MFMA16(ah[i], bl[j], acc[i][j]);

        if (sd == 7) {
            const int cbase = ct * 256 + wn * 128;
            #pragma unroll
            for (int j = 0; j < 8; ++j) {
                const int col = cbase + j * 16 + l15;
                const float e2v = e2s[col];
                #pragma unroll
                for (int i = 0; i < 4; ++i)
                    #pragma unroll
                    for (int r = 0; r < 4; ++r) {
                        float m = fmaf(-2.0f, acc[i][j][r], e2v);
                        const int tt_ = i * 4 + r;
                        if (m < best[tt_]) { best[tt_] = m; bidx[tt_] = col; }
                    }
            }
        }
    }

    __syncthreads();
    float* rv = (float*)lds;
    int*   ri = (int*)(lds + 4096);
    #pragma unroll
    for (int tt_ = 0; tt_ < 16; ++tt_) {
        float v = best[tt_];
        int  ix = bidx[tt_];
        #pragma unroll
        for (int m = 1; m <= 8; m <<= 1) {
            float ov = __shfl_xor(v, m, 64);
            int  oix = __shfl_xor(ix, m, 64);
            if (ov < v || (ov == v && oix < ix)) { v = ov; ix = oix; }
        }
        if (l15 == 0) {
            const int rl = wm * 64 + (tt_ >> 2) * 16 + l4 * 4 + (tt_ & 3);
            rv[rl * 2 + wn] = v;
            ri[rl * 2 + wn] = ix;
        }
    }
    __syncthreads();
    if (tid < 256) {
        float v0 = rv[tid * 2], v1 = rv[tid * 2 + 1];
        int   i0 = ri[tid * 2], i1 = ri[tid * 2 + 1];
        int ibc = (v1 < v0 || (v1 == v0 && i1 < i0)) ? i1 : i0;
        int ib = cmap[ibc];            // back to original code index
        flat_ind[row0 + tid] = ib;
        unsigned long long pending = ~0ULL;
        while (pending) {
            int leader = __ffsll((long long)pending) - 1;
            int lind = __shfl(ib, leader, 64);
            unsigned long long same = __ballot(ib == lind);
            if ((tid & 63) == leader) atomicAdd(&cnt[lind], (int)__popcll(same));
            pending &= ~same;
        }
    }
}

// ---------------------------------------------------------------------------
// scan: exclusive prefix sum over 2048 counts -> offsets, cursor
// ---------------------------------------------------------------------------
__global__ __launch_bounds__(256) void scan_kernel(
    const int* __restrict__ cnt, int* __restrict__ offs, int* __restrict__ cursor)
{
    __shared__ int ps[256];
    const int t = threadIdx.x;
    int pre[8], s = 0;
    #pragma unroll
    for (int j = 0; j < 8; ++j) { pre[j] = s; s += cnt[t * 8 + j]; }
    ps[t] = s;
    __syncthreads();
    for (int off = 1; off < 256; off <<= 1) {
        int v = (t >= off) ? ps[t - off] : 0;
        __syncthreads();
        ps[t] += v;
        __syncthreads();
    }
    int ex = (t > 0) ? ps[t - 1] : 0;
    #pragma unroll
    for (int j = 0; j < 8; ++j) {
        offs[t * 8 + j]   = ex + pre[j];
        cursor[t * 8 + j] = ex + pre[j];
    }
}

// ---------------------------------------------------------------------------
// assign: counting-sort placement with wave-aggregated cursor atomics.
// ---------------------------------------------------------------------------
__global__ __launch_bounds__(256) void assign_kernel(
    const int* __restrict__ flat_ind, int* __restrict__ cursor,
    int* __restrict__ rowlist, int* __restrict__ codesorted)
{
    const int i    = blockIdx.x * 256 + threadIdx.x;
    const int lane = threadIdx.x & 63;
    const int ind  = flat_ind[i];
    int pos = 0;
    unsigned long long pending = ~0ULL;
    while (pending) {
        int leader = __ffsll((long long)pending) - 1;
        int lind = __shfl(ind, leader, 64);
        unsigned long long same = __ballot(ind == lind);
        if (ind == lind) {
            int base = 0;
            if (lane == leader) base = atomicAdd(&cursor[lind], (int)__popcll(same));
            base = __shfl(base, leader, 64);
            pos = base + (int)__popcll(same & ((1ULL << lane) - 1ULL));
        }
        pending &= ~same;
    }
    rowlist[pos] = i;
    codesorted[pos] = ind;
}

// ---------------------------------------------------------------------------
// codesum + fused quantize: chunked segmented reduction over sorted rows
// (skew-proof); also writes out_q[row] = embed[code] and out_ind[row].
// ---------------------------------------------------------------------------
__global__ __launch_bounds__(256) void codesum_kernel(
    const float* __restrict__ x, const int* __restrict__ rowlist,
    const int* __restrict__ codesorted, float* __restrict__ sums,
    const float* __restrict__ embed, float* __restrict__ out_q,
    float* __restrict__ out_ind_f)
{
    const int p0 = blockIdx.x * 64;
    __shared__ int rows[64], codes[64];
    if (threadIdx.x < 64) {
        rows[threadIdx.x]  = rowlist[p0 + threadIdx.x];
        codes[threadIdx.x] = codesorted[p0 + threadIdx.x];
    }
    __syncthreads();
    const int d = threadIdx.x;
    float acc = 0.f;
    int cur = codes[0];
    #pragma unroll 4
    for (int r = 0; r < 64; ++r) {
        const int c = codes[r];
        const int row = rows[r];
        if (c != cur) {
            atomicAdd(&sums[(size_t)cur * DIM + d], acc);
            acc = 0.f; cur = c;
        }
        acc += x[(size_t)row * DIM + d];
        out_q[(size_t)row * DIM + d] = embed[(size_t)c * DIM + d];
        if (d == 0) out_ind_f[row] = (float)c;
    }
    atomicAdd(&sums[(size_t)cur * DIM + d], acc);
}

// ---------------------------------------------------------------------------
// finalize: EMA update outputs
// ---------------------------------------------------------------------------
__global__ __launch_bounds__(256) void finalize_kernel(
    const float* __restrict__ embed_sum, const float* __restrict__ usage,
    const float* __restrict__ sums, const int* __restrict__ cnt,
    float* __restrict__ out_usage, float* __restrict__ out_es)
{
    const int k = blockIdx.x, d = threadIdx.x;
    out_es[k * DIM + d] = embed_sum[k * DIM + d] * DECAYF + sums[k * DIM + d] * (1.0f - DECAYF);
    if (d == 0)
        out_usage[k] = usage[k] * DECAYF + (float)cnt[k] * (1.0f - DECAYF);
}

extern "C" void kernel_launch(void* const* d_in, const int* in_sizes, int n_in,
                              void* d_out, int out_size, void* d_ws, size_t ws_size,
                              hipStream_t stream)
{
    const float* hs        = (const float*)d_in[0];
    const float* embed_sum = (const float*)d_in[1];
    const float* usage     = (const float*)d_in[2];
    const int N = in_sizes[0] / DIM;   // 65536

    float* ws_f      = (float*)d_ws;
    float* embed     = ws_f;                         // K*D f32
    float* e2        = embed + KCODES * DIM;         // K
    float* sums      = e2 + KCODES;                  // K*D f32  (memset w/ cnt)
    int*   cnt       = (int*)(sums + KCODES * DIM);  // K        (adjacent)
    f16*   eh        = (f16*)(cnt + KCODES);         // K*D f16
    f16*   el        = eh + KCODES * DIM;            // K*D f16
    f16*   ceh       = el + KCODES * DIM;            // K*D f16 (compacted)
    f16*   cel       = ceh + KCODES * DIM;           // K*D f16
    float* ce2       = (float*)(cel + KCODES * DIM); // K
    int*   cmap      = (int*)(ce2 + KCODES);         // K
    int*   cpos      = cmap + KCODES;                // K
    int*   meta      = cpos + KCODES;                // 16
    unsigned* stats  = (unsigned*)(meta + 16);       // [0]=maxx2, [1]=mine2
    int*   offs      = (int*)(stats + 2);            // K
    int*   cursor    = offs + KCODES;                // K
    int*   rowlist   = cursor + KCODES;              // N
    int*   codesorted= rowlist + N;                  // N
    int*   flat_ind  = codesorted + N;               // N

    float* out_q     = (float*)d_out;                // N*D
    float* out_ind   = out_q + (size_t)N * DIM;      // N
    float* out_usage = out_ind + N;                  // K
    float* out_es    = out_usage + KCODES;           // K*D

    // xh/xl live in the out_q region (exactly N*D*4B); dead after argmin,
    // codesum overwrites out_q afterwards.
    f16* xh = (f16*)out_q;
    f16* xl = xh + (size_t)N * DIM;

    hipMemsetAsync(sums, 0, (size_t)(KCODES * DIM + KCODES) * sizeof(float), stream);
    hipMemsetAsync(stats, 0x00, 4, stream);          // maxx2 = 0
    hipMemsetAsync(stats + 1, 0xFF, 4, stream);      // mine2 = UINT_MAX

    const int nsplit = N * DIM / 8 / 256;            // 8192
    split_prep_kernel<<<nsplit + KCODES, 256, 0, stream>>>(
        hs, xh, xl, nsplit, embed_sum, usage, embed, eh, el, e2, stats, stats + 1);
    compactA_kernel<<<1, 256, 0, stream>>>(e2, stats, stats + 1, cpos, ce2, cmap, meta);
    compactB_kernel<<<KCODES + 256, 256, 0, stream>>>(eh, el, cpos, meta, ceh, cel);
    argmin_kernel<<<N / 256, 512, 0, stream>>>(xh, xl, ceh, cel, ce2, cmap, meta,
                                               flat_ind, cnt);
    scan_kernel<<<1, 256, 0, stream>>>(cnt, offs, cursor);
    assign_kernel<<<N / 256, 256, 0, stream>>>(flat_ind, cursor, rowlist, codesorted);
    codesum_kernel<<<N / 64, 256, 0, stream>>>(hs, rowlist, codesorted, sums,
                                               embed, out_q, out_ind);
    finalize_kernel<<<KCODES, 256, 0, stream>>>(embed_sum, usage, sums, cnt,
                                                out_usage, out_es);
}

// Round 10
// 352.589 us; speedup vs baseline: 1.0017x; 1.0017x over previous
//
#include <hip/hip_runtime.h>

#define EPSF 1e-5f
#define DECAYF 0.99f
#define KCODES 2048
#define DIM 256

typedef _Float16 f16;
typedef f16 f16x8 __attribute__((ext_vector_type(8)));
typedef float f32x4 __attribute__((ext_vector_type(4)));

#define MFMA16(A, B, C) __builtin_amdgcn_mfma_f32_16x16x32_f16(A, B, C, 0, 0, 0)

#define OFF_AH 0
#define OFF_AL 16384
#define OFF_BH 32768
#define OFF_BL 49152

__device__ __forceinline__ void gload_lds16(const void* g, void* l) {
    __builtin_amdgcn_global_load_lds(
        (const __attribute__((address_space(1))) void*)g,
        (__attribute__((address_space(3))) void*)l, 16, 0, 0);
}

// ---------------------------------------------------------------------------
// fused split_x + prep_embed; also accumulates max_x2 and min_e2 stats.
// ---------------------------------------------------------------------------
__global__ __launch_bounds__(256) void split_prep_kernel(
    const float* __restrict__ x, f16* __restrict__ xh, f16* __restrict__ xl, int nsplit,
    const float* __restrict__ embed_sum, const float* __restrict__ usage,
    float* __restrict__ embed, f16* __restrict__ eh, f16* __restrict__ el,
    float* __restrict__ e2, unsigned* __restrict__ maxx2_u, unsigned* __restrict__ mine2_u)
{
    if ((int)blockIdx.x < nsplit) {
        int i = blockIdx.x * 256 + threadIdx.x;
        f32x4 v0 = ((const f32x4*)x)[2 * i];
        f32x4 v1 = ((const f32x4*)x)[2 * i + 1];
        f16x8 h, l;
        float p = 0.f;
        #pragma unroll
        for (int t = 0; t < 4; ++t) {
            f16 h0 = (f16)v0[t]; h[t] = h0; l[t] = (f16)(v0[t] - (float)h0);
            f16 h1 = (f16)v1[t]; h[t + 4] = h1; l[t + 4] = (f16)(v1[t] - (float)h1);
            p += v0[t] * v0[t] + v1[t] * v1[t];
        }
        ((f16x8*)xh)[i] = h;
        ((f16x8*)xl)[i] = l;
        // per-row x2: 32 consecutive lanes cover one row (8 elems each)
        #pragma unroll
        for (int m = 1; m <= 16; m <<= 1) p += __shfl_xor(p, m, 64);
        float q = fmaxf(p, __shfl_xor(p, 32, 64));
        __shared__ float wmax[4];
        if ((threadIdx.x & 63) == 0) wmax[threadIdx.x >> 6] = q;
        __syncthreads();
        if (threadIdx.x == 0) {
            float bm = fmaxf(fmaxf(wmax[0], wmax[1]), fmaxf(wmax[2], wmax[3]));
            atomicMax(maxx2_u, __float_as_uint(bm));
        }
    } else {
        int k = blockIdx.x - nsplit;
        int d = threadIdx.x;
        float inv = 1.0f / fmaxf(usage[k], EPSF);
        float e = embed_sum[k * DIM + d] * inv;
        embed[k * DIM + d] = e;
        float ec = fminf(fmaxf(e, -65000.0f), 65000.0f);
        f16 h = (f16)ec;
        f16 l = (f16)(ec - (float)h);
        eh[k * DIM + d] = h;
        el[k * DIM + d] = l;
        float sq = e * e;
        #pragma unroll
        for (int off = 32; off > 0; off >>= 1) sq += __shfl_down(sq, off, 64);
        __shared__ float ws[4];
        if ((threadIdx.x & 63) == 0) ws[threadIdx.x >> 6] = sq;
        __syncthreads();
        if (threadIdx.x == 0) {
            float s = ws[0] + ws[1] + ws[2] + ws[3];
            e2[k] = s;
            atomicMin(mine2_u, __float_as_uint(s));
        }
    }
}

// ---------------------------------------------------------------------------
// compactA: exact prune threshold + STABLE compaction plan (1 block).
// ---------------------------------------------------------------------------
__global__ __launch_bounds__(256) void compactA_kernel(
    const float* __restrict__ e2, const unsigned* __restrict__ maxx2_u,
    const unsigned* __restrict__ mine2_u, int* __restrict__ cpos,
    float* __restrict__ ce2, int* __restrict__ cmap, int* __restrict__ meta)
{
    __shared__ int ps[256];
    const int t = threadIdx.x;
    const float T0 = 2.0f * sqrtf(__uint_as_float(*maxx2_u)) + sqrtf(__uint_as_float(*mine2_u));
    const float T = T0 * T0 * 1.0002f + 1.0f;
    int flag[8], pre[8], s = 0;
    float ev[8];
    #pragma unroll
    for (int j = 0; j < 8; ++j) {
        ev[j] = e2[t * 8 + j];
        flag[j] = (ev[j] <= T) ? 1 : 0;
        pre[j] = s; s += flag[j];
    }
    ps[t] = s;
    __syncthreads();
    for (int off = 1; off < 256; off <<= 1) {
        int v = (t >= off) ? ps[t - off] : 0;
        __syncthreads();
        ps[t] += v;
        __syncthreads();
    }
    const int ex = (t > 0) ? ps[t - 1] : 0;
    const int kp = ps[255];
    #pragma unroll
    for (int j = 0; j < 8; ++j) {
        const int k = t * 8 + j;
        if (flag[j]) {
            const int p = ex + pre[j];
            cpos[k] = p;
            ce2[p] = ev[j];
            cmap[p] = k;
        } else cpos[k] = -1;
    }
    for (int j = t; j < KCODES; j += 256)
        if (j >= kp) { ce2[j] = 3.4e38f; cmap[j] = 0; }
    if (t == 0) { meta[0] = kp; meta[1] = (kp + 255) & ~255; }
}

// ---------------------------------------------------------------------------
// compactB: gather flagged eh/el rows into ceh/cel; zero the pad rows.
// ---------------------------------------------------------------------------
__global__ __launch_bounds__(256) void compactB_kernel(
    const f16* __restrict__ eh, const f16* __restrict__ el, const int* __restrict__ cpos,
    const int* __restrict__ meta, f16* __restrict__ ceh, f16* __restrict__ cel)
{
    const int b = blockIdx.x, t = threadIdx.x;
    if (b < KCODES) {
        const int p = cpos[b];
        if (p >= 0) {
            ceh[p * DIM + t] = eh[b * DIM + t];
            cel[p * DIM + t] = el[b * DIM + t];
        }
    } else {
        const int slot = meta[0] + (b - KCODES);
        if (slot < meta[1]) {
            ceh[slot * DIM + t] = (f16)0.f;
            cel[slot * DIM + t] = (f16)0.f;
        }
    }
}

// ---------------------------------------------------------------------------
// argmin: round-7 structure over the COMPACTED codebook (157us proven).
// ---------------------------------------------------------------------------
__global__ __launch_bounds__(512, 2) void argmin_kernel(
    const f16* __restrict__ xh, const f16* __restrict__ xl,
    const f16* __restrict__ ceh, const f16* __restrict__ cel,
    const float* __restrict__ ce2, const int* __restrict__ cmap,
    const int* __restrict__ meta, int* __restrict__ flat_ind, int* __restrict__ cnt)
{
    __shared__ __align__(1024) char lds[2 * 65536 + 8192];
    float* e2s = (float*)(lds + 131072);

    const int ncc = meta[1] >> 5;
    const int tid  = threadIdx.x;
    const int w    = tid >> 6, lane = tid & 63;
    const int l15  = lane & 15, l4 = lane >> 4;
    const int wm   = w >> 1, wn = w & 1;
    const int row0 = blockIdx.x * 256;
    const int gsw  = (lane & 3) ^ ((lane >> 3) & 3);
    const int lq   = lane >> 2;
    const int rslot = (l4 ^ ((l15 >> 1) & 3)) * 16;

    f32x4 acc[4][8];
    float best[16];
    int   bidx[16];
    #pragma unroll
    for (int t = 0; t < 16; ++t) { best[t] = 3.4e38f; bidx[t] = 0; }

    auto stageU = [&](const f16* rowbase, int koff, char* unit) {
        #pragma unroll
        for (int q = 0; q < 2; ++q) {
            const int r = w * 32 + q * 16 + lq;
            gload_lds16(rowbase + (size_t)r * DIM + koff + gsw * 8,
                        unit + w * 2048 + q * 1024 + lane * 16);
        }
    };

    ((f32x4*)e2s)[tid] = ((const f32x4*)ce2)[tid];
    stageU(xh + (size_t)row0 * DIM, 0, lds + OFF_AH);
    stageU(xl + (size_t)row0 * DIM, 0, lds + OFF_AL);
    stageU(ceh, 0, lds + OFF_BH);
    stageU(cel, 0, lds + OFF_BL);

    for (int cc = 0; cc < ncc; ++cc) {
        char* buf  = lds + (cc & 1) * 65536;
        char* nbuf = lds + ((cc + 1) & 1) * 65536;
        const int ct = cc >> 3, sd = cc & 7;
        const int nn = cc + 1;
        const int nct = nn >> 3, nsd = nn & 7;
        const bool more = (nn < ncc);

        if (sd == 0) {
            #pragma unroll
            for (int i = 0; i < 4; ++i)
                #pragma unroll
                for (int j = 0; j < 8; ++j)
                    acc[i][j] = (f32x4){0.f, 0.f, 0.f, 0.f};
        }

        asm volatile("s_waitcnt vmcnt(0)" ::: "memory");
        __builtin_amdgcn_s_barrier();
        __builtin_amdgcn_sched_barrier(0);

        if (more) {
            stageU(xh + (size_t)row0 * DIM, nsd * 32, nbuf + OFF_AH);
            stageU(xl + (size_t)row0 * DIM, nsd * 32, nbuf + OFF_AL);
            stageU(ceh + (size_t)(nct * 256) * DIM, nsd * 32, nbuf + OFF_BH);
            stageU(cel + (size_t)(nct * 256) * DIM, nsd * 32, nbuf + OFF_BL);
        }

        f16x8 ah[4], al[4], bh[8], bl[8];
        #pragma unroll
        for (int i = 0; i < 4; ++i)
            ah[i] = *(const f16x8*)(buf + OFF_AH + (wm * 64 + i * 16 + l15) * 64 + rslot);
        #pragma unroll
        for (int j = 0; j < 8; ++j)
            bh[j] = *(const f16x8*)(buf + OFF_BH + (wn * 128 + j * 16 + l15) * 64 + rslot);
        #pragma unroll
        for (int i = 0; i < 4; ++i)
            al[i] = *(const f16x8*)(buf + OFF_AL + (wm * 64 + i * 16 + l15) * 64 + rslot);

        #pragma unroll
        for (int i = 0; i < 4; ++i)
            #pragma unroll
            for (int j = 0; j < 8; ++j)
                acc[i][j] = MFMA16(ah[i], bh[j], acc[i][j]);
        #pragma unroll
        for (int i = 0; i < 4; ++i)
            #pragma unroll
            for (int j = 0; j < 8; ++j)
                acc[i][j] = MFMA16(al[i], bh[j], acc[i][j]);

        #pragma unroll
        for (int j = 0; j < 8; ++j)
            bl[j] = *(const f16x8*)(buf + OFF_BL + (wn * 128 + j * 16 + l15) * 64 + rslot);
        #pragma unroll
        for (int i = 0; i < 4; ++i)
            #pragma unroll
            for (int j = 0; j < 8; ++j)
                acc[i][j] = MFMA16(ah[i], bl[j], acc[i][j]);

        if (sd == 7) {
            const int cbase = ct * 256 + wn * 128;
            #pragma unroll
            for (int j = 0; j < 8; ++j) {
                const int col = cbase + j * 16 + l15;
                const float e2v = e2s[col];
                #pragma unroll
                for (int i = 0; i < 4; ++i)
                    #pragma unroll
                    for (int r = 0; r < 4; ++r) {
                        float m = fmaf(-2.0f, acc[i][j][r], e2v);
                        const int tt_ = i * 4 + r;
                        if (m < best[tt_]) { best[tt_] = m; bidx[tt_] = col; }
                    }
            }
        }
    }

    __syncthreads();
    float* rv = (float*)lds;
    int*   ri = (int*)(lds + 4096);
    #pragma unroll
    for (int tt_ = 0; tt_ < 16; ++tt_) {
        float v = best[tt_];
        int  ix = bidx[tt_];
        #pragma unroll
        for (int m = 1; m <= 8; m <<= 1) {
            float ov = __shfl_xor(v, m, 64);
            int  oix = __shfl_xor(ix, m, 64);
            if (ov < v || (ov == v && oix < ix)) { v = ov; ix = oix; }
        }
        if (l15 == 0) {
            const int rl = wm * 64 + (tt_ >> 2) * 16 + l4 * 4 + (tt_ & 3);
            rv[rl * 2 + wn] = v;
            ri[rl * 2 + wn] = ix;
        }
    }
    __syncthreads();
    if (tid < 256) {
        float v0 = rv[tid * 2], v1 = rv[tid * 2 + 1];
        int   i0 = ri[tid * 2], i1 = ri[tid * 2 + 1];
        int ibc = (v1 < v0 || (v1 == v0 && i1 < i0)) ? i1 : i0;
        int ib = cmap[ibc];
        flat_ind[row0 + tid] = ib;
        unsigned long long pending = ~0ULL;
        while (pending) {
            int leader = __ffsll((long long)pending) - 1;
            int lind = __shfl(ib, leader, 64);
            unsigned long long same = __ballot(ib == lind);
            if ((tid & 63) == leader) atomicAdd(&cnt[lind], (int)__popcll(same));
            pending &= ~same;
        }
    }
}

// ---------------------------------------------------------------------------
// scan: exclusive prefix sum over 2048 counts -> offsets, cursor
// ---------------------------------------------------------------------------
__global__ __launch_bounds__(256) void scan_kernel(
    const int* __restrict__ cnt, int* __restrict__ offs, int* __restrict__ cursor)
{
    __shared__ int ps[256];
    const int t = threadIdx.x;
    int pre[8], s = 0;
    #pragma unroll
    for (int j = 0; j < 8; ++j) { pre[j] = s; s += cnt[t * 8 + j]; }
    ps[t] = s;
    __syncthreads();
    for (int off = 1; off < 256; off <<= 1) {
        int v = (t >= off) ? ps[t - off] : 0;
        __syncthreads();
        ps[t] += v;
        __syncthreads();
    }
    int ex = (t > 0) ? ps[t - 1] : 0;
    #pragma unroll
    for (int j = 0; j < 8; ++j) {
        offs[t * 8 + j]   = ex + pre[j];
        cursor[t * 8 + j] = ex + pre[j];
    }
}

// ---------------------------------------------------------------------------
// assign: counting-sort placement with wave-aggregated cursor atomics.
// ---------------------------------------------------------------------------
__global__ __launch_bounds__(256) void assign_kernel(
    const int* __restrict__ flat_ind, int* __restrict__ cursor,
    int* __restrict__ rowlist, int* __restrict__ codesorted)
{
    const int i    = blockIdx.x * 256 + threadIdx.x;
    const int lane = threadIdx.x & 63;
    const int ind  = flat_ind[i];
    int pos = 0;
    unsigned long long pending = ~0ULL;
    while (pending) {
        int leader = __ffsll((long long)pending) - 1;
        int lind = __shfl(ind, leader, 64);
        unsigned long long same = __ballot(ind == lind);
        if (ind == lind) {
            int base = 0;
            if (lane == leader) base = atomicAdd(&cursor[lind], (int)__popcll(same));
            base = __shfl(base, leader, 64);
            pos = base + (int)__popcll(same & ((1ULL << lane) - 1ULL));
        }
        pending &= ~same;
    }
    rowlist[pos] = i;
    codesorted[pos] = ind;
}

// ---------------------------------------------------------------------------
// codesum: pure chunked segmented reduction over sorted rows (skew-proof).
// ---------------------------------------------------------------------------
__global__ __launch_bounds__(256) void codesum_kernel(
    const float* __restrict__ x, const int* __restrict__ rowlist,
    const int* __restrict__ codesorted, float* __restrict__ sums)
{
    const int p0 = blockIdx.x * 64;
    __shared__ int rows[64], codes[64];
    if (threadIdx.x < 64) {
        rows[threadIdx.x]  = rowlist[p0 + threadIdx.x];
        codes[threadIdx.x] = codesorted[p0 + threadIdx.x];
    }
    __syncthreads();
    const int d = threadIdx.x;
    float acc = 0.f;
    int cur = codes[0];
    #pragma unroll 4
    for (int r = 0; r < 64; ++r) {
        const int c = codes[r];
        if (c != cur) {
            atomicAdd(&sums[(size_t)cur * DIM + d], acc);
            acc = 0.f; cur = c;
        }
        acc += x[(size_t)rows[r] * DIM + d];
    }
    atomicAdd(&sums[(size_t)cur * DIM + d], acc);
}

// ---------------------------------------------------------------------------
// fused quantize + finalize (wide streaming, round-8 proven)
// blocks [0, nq): out_q = embed[flat_ind], out_ind = (float)flat_ind
// blocks [nq, nq+K): EMA outputs from sums/cnt
// ---------------------------------------------------------------------------
__global__ __launch_bounds__(256) void quant_final_kernel(
    const float* __restrict__ embed, const int* __restrict__ flat_ind,
    float* __restrict__ out_q, float* __restrict__ out_ind_f, int N, int nq,
    const float* __restrict__ embed_sum, const float* __restrict__ usage,
    const float* __restrict__ sums, const int* __restrict__ cnt,
    float* __restrict__ out_usage, float* __restrict__ out_es)
{
    if ((int)blockIdx.x < nq) {
        int i = blockIdx.x * 256 + threadIdx.x;   // over N*64 float4s
        int row = i >> 6, c4 = i & 63;
        int ind = flat_ind[row];
        ((f32x4*)out_q)[i] = ((const f32x4*)embed)[ind * 64 + c4];
        if (i < N) out_ind_f[i] = (float)flat_ind[i];
    } else {
        const int k = blockIdx.x - nq, d = threadIdx.x;
        out_es[k * DIM + d] = embed_sum[k * DIM + d] * DECAYF + sums[k * DIM + d] * (1.0f - DECAYF);
        if (d == 0)
            out_usage[k] = usage[k] * DECAYF + (float)cnt[k] * (1.0f - DECAYF);
    }
}

extern "C" void kernel_launch(void* const* d_in, const int* in_sizes, int n_in,
                              void* d_out, int out_size, void* d_ws, size_t ws_size,
                              hipStream_t stream)
{
    const float* hs        = (const float*)d_in[0];
    const float* embed_sum = (const float*)d_in[1];
    const float* usage     = (const float*)d_in[2];
    const int N = in_sizes[0] / DIM;   // 65536

    float* ws_f      = (float*)d_ws;
    float* embed     = ws_f;                         // K*D f32
    float* e2        = embed + KCODES * DIM;         // K
    float* sums      = e2 + KCODES;                  // K*D f32  (memset w/ cnt)
    int*   cnt       = (int*)(sums + KCODES * DIM);  // K        (adjacent)
    f16*   eh        = (f16*)(cnt + KCODES);         // K*D f16
    f16*   el        = eh + KCODES * DIM;            // K*D f16
    f16*   ceh       = el + KCODES * DIM;            // K*D f16 (compacted)
    f16*   cel       = ceh + KCODES * DIM;           // K*D f16
    float* ce2       = (float*)(cel + KCODES * DIM); // K
    int*   cmap      = (int*)(ce2 + KCODES);         // K
    int*   cpos      = cmap + KCODES;                // K
    int*   meta      = cpos + KCODES;                // 16
    unsigned* stats  = (unsigned*)(meta + 16);       // [0]=maxx2, [1]=mine2
    int*   offs      = (int*)(stats + 2);            // K
    int*   cursor    = offs + KCODES;                // K
    int*   rowlist   = cursor + KCODES;              // N
    int*   codesorted= rowlist + N;                  // N
    int*   flat_ind  = codesorted + N;               // N

    float* out_q     = (float*)d_out;                // N*D
    float* out_ind   = out_q + (size_t)N * DIM;      // N
    float* out_usage = out_ind + N;                  // K
    float* out_es    = out_usage + KCODES;           // K*D

    // xh/xl live in the out_q region (exactly N*D*4B); dead after argmin,
    // quant_final overwrites out_q afterwards.
    f16* xh = (f16*)out_q;
    f16* xl = xh + (size_t)N * DIM;

    hipMemsetAsync(sums, 0, (size_t)(KCODES * DIM + KCODES) * sizeof(float), stream);
    hipMemsetAsync(stats, 0x00, 4, stream);          // maxx2 = 0
    hipMemsetAsync(stats + 1, 0xFF, 4, stream);      // mine2 = UINT_MAX

    const int nsplit = N * DIM / 8 / 256;            // 8192
    split_prep_kernel<<<nsplit + KCODES, 256, 0, stream>>>(
        hs, xh, xl, nsplit, embed_sum, usage, embed, eh, el, e2, stats, stats + 1);
    compactA_kernel<<<1, 256, 0, stream>>>(e2, stats, stats + 1, cpos, ce2, cmap, meta);
    compactB_kernel<<<KCODES + 256, 256, 0, stream>>>(eh, el, cpos, meta, ceh, cel);
    argmin_kernel<<<N / 256, 512, 0, stream>>>(xh, xl, ceh, cel, ce2, cmap, meta,
                                               flat_ind, cnt);
    scan_kernel<<<1, 256, 0, stream>>>(cnt, offs, cursor);
    assign_kernel<<<N / 256, 256, 0, stream>>>(flat_ind, cursor, rowlist, codesorted);
    codesum_kernel<<<N / 64, 256, 0, stream>>>(hs, rowlist, codesorted, sums);
    const int nq = N * DIM / 4 / 256;                // 16384
    quant_final_kernel<<<nq + KCODES, 256, 0, stream>>>(
        embed, flat_ind, out_q, out_ind, N, nq,
        embed_sum, usage, sums, cnt, out_usage, out_es);
}

// Round 11
// 279.608 us; speedup vs baseline: 1.2631x; 1.2610x over previous
//
#include <hip/hip_runtime.h>

#define EPSF 1e-5f
#define DECAYF 0.99f
#define KCODES 2048
#define DIM 256

typedef _Float16 f16;
typedef f16 f16x8 __attribute__((ext_vector_type(8)));
typedef float f32x4 __attribute__((ext_vector_type(4)));

#define MFMA16(A, B, C) __builtin_amdgcn_mfma_f32_16x16x32_f16(A, B, C, 0, 0, 0)

#define OFF_AH 0
#define OFF_AL 16384
#define OFF_BH 32768
#define OFF_BL 49152

__device__ __forceinline__ void gload_lds16(const void* g, void* l) {
    __builtin_amdgcn_global_load_lds(
        (const __attribute__((address_space(1))) void*)g,
        (__attribute__((address_space(3))) void*)l, 16, 0, 0);
}

// ---------------------------------------------------------------------------
// fused split_x + prep_embed; stats via 64-slot partial atomics (low
// contention, Guideline 12). Keys are order-preserving uint encodings so
// both reductions are atomicMax and both initialize to 0x00000000:
//   maxx2 key = u(x2) | 0x80000000          (x2 >= 0)
//   mine2 key = ~u(-e2)                     (bigger key = smaller e2)
// ---------------------------------------------------------------------------
__global__ __launch_bounds__(256) void split_prep_kernel(
    const float* __restrict__ x, f16* __restrict__ xh, f16* __restrict__ xl, int nsplit,
    const float* __restrict__ embed_sum, const float* __restrict__ usage,
    float* __restrict__ embed, f16* __restrict__ eh, f16* __restrict__ el,
    float* __restrict__ e2, unsigned* __restrict__ pmax, unsigned* __restrict__ pmin)
{
    if ((int)blockIdx.x < nsplit) {
        int i = blockIdx.x * 256 + threadIdx.x;
        f32x4 v0 = ((const f32x4*)x)[2 * i];
        f32x4 v1 = ((const f32x4*)x)[2 * i + 1];
        f16x8 h, l;
        float p = 0.f;
        #pragma unroll
        for (int t = 0; t < 4; ++t) {
            f16 h0 = (f16)v0[t]; h[t] = h0; l[t] = (f16)(v0[t] - (float)h0);
            f16 h1 = (f16)v1[t]; h[t + 4] = h1; l[t + 4] = (f16)(v1[t] - (float)h1);
            p += v0[t] * v0[t] + v1[t] * v1[t];
        }
        ((f16x8*)xh)[i] = h;
        ((f16x8*)xl)[i] = l;
        // per-row x2: 32 consecutive lanes cover one row (8 elems each)
        #pragma unroll
        for (int m = 1; m <= 16; m <<= 1) p += __shfl_xor(p, m, 64);
        float q = fmaxf(p, __shfl_xor(p, 32, 64));
        __shared__ float wmax[4];
        if ((threadIdx.x & 63) == 0) wmax[threadIdx.x >> 6] = q;
        __syncthreads();
        if (threadIdx.x == 0) {
            float bm = fmaxf(fmaxf(wmax[0], wmax[1]), fmaxf(wmax[2], wmax[3]));
            atomicMax(&pmax[blockIdx.x & 63], __float_as_uint(bm) | 0x80000000u);
        }
    } else {
        int k = blockIdx.x - nsplit;
        int d = threadIdx.x;
        float inv = 1.0f / fmaxf(usage[k], EPSF);
        float e = embed_sum[k * DIM + d] * inv;
        embed[k * DIM + d] = e;
        float ec = fminf(fmaxf(e, -65000.0f), 65000.0f);
        f16 h = (f16)ec;
        f16 l = (f16)(ec - (float)h);
        eh[k * DIM + d] = h;
        el[k * DIM + d] = l;
        float sq = e * e;
        #pragma unroll
        for (int off = 32; off > 0; off >>= 1) sq += __shfl_down(sq, off, 64);
        __shared__ float ws[4];
        if ((threadIdx.x & 63) == 0) ws[threadIdx.x >> 6] = sq;
        __syncthreads();
        if (threadIdx.x == 0) {
            float s = ws[0] + ws[1] + ws[2] + ws[3];
            e2[k] = s;
            atomicMax(&pmin[k & 63], ~__float_as_uint(-s));
        }
    }
}

// ---------------------------------------------------------------------------
// compactA: reduce 64-slot stats -> exact prune threshold; STABLE compaction
// plan (1 block). Winner bound: ||e_k|| <= 2*max||x|| + min||e||. Produces
// ce2 (padded with +inf sentinels) and cmap only — eh/el are NOT gathered;
// argmin stages them indirectly through cmap.
// ---------------------------------------------------------------------------
__global__ __launch_bounds__(256) void compactA_kernel(
    const float* __restrict__ e2, const unsigned* __restrict__ pmax,
    const unsigned* __restrict__ pmin, float* __restrict__ ce2,
    int* __restrict__ cmap, int* __restrict__ meta)
{
    __shared__ int ps[256];
    __shared__ float sT;
    const int t = threadIdx.x;
    if (t < 64) {
        unsigned km = pmax[t], kn = pmin[t];
        #pragma unroll
        for (int m = 1; m <= 32; m <<= 1) {
            km = max(km, (unsigned)__shfl_xor((int)km, m, 64));
            kn = max(kn, (unsigned)__shfl_xor((int)kn, m, 64));
        }
        if (t == 0) {
            float mx = __uint_as_float(km & 0x7FFFFFFFu);   // max ||x||^2
            float mn = -__uint_as_float(~kn);               // min ||e||^2
            float T0 = 2.0f * sqrtf(mx) + sqrtf(mn);
            sT = T0 * T0 * 1.0002f + 1.0f;
        }
    }
    __syncthreads();
    const float T = sT;
    int flag[8], pre[8], s = 0;
    float ev[8];
    #pragma unroll
    for (int j = 0; j < 8; ++j) {
        ev[j] = e2[t * 8 + j];
        flag[j] = (ev[j] <= T) ? 1 : 0;
        pre[j] = s; s += flag[j];
    }
    ps[t] = s;
    __syncthreads();
    for (int off = 1; off < 256; off <<= 1) {
        int v = (t >= off) ? ps[t - off] : 0;
        __syncthreads();
        ps[t] += v;
        __syncthreads();
    }
    const int ex = (t > 0) ? ps[t - 1] : 0;
    const int kp = ps[255];
    #pragma unroll
    for (int j = 0; j < 8; ++j) {
        const int k = t * 8 + j;
        if (flag[j]) {
            const int p = ex + pre[j];
            ce2[p] = ev[j];
            cmap[p] = k;
        }
    }
    for (int j = t; j < KCODES; j += 256)
        if (j >= kp) { ce2[j] = 3.4e38f; cmap[j] = 0; }
    if (t == 0) { meta[0] = kp; meta[1] = (kp + 255) & ~255; }
}

// ---------------------------------------------------------------------------
// argmin: round-7 structure (157us proven) over the pruned codebook, with
// INDIRECT B staging: physical code row = cmap[compact_col] resolved per-lane
// at stage time (global source of global_load_lds is per-lane; cmap is 8KB,
// L2-resident, loaded one chunk ahead of use).
// ---------------------------------------------------------------------------
__global__ __launch_bounds__(512, 2) void argmin_kernel(
    const f16* __restrict__ xh, const f16* __restrict__ xl,
    const f16* __restrict__ eh, const f16* __restrict__ el,
    const float* __restrict__ ce2, const int* __restrict__ cmap,
    const int* __restrict__ meta, int* __restrict__ flat_ind, int* __restrict__ cnt)
{
    __shared__ __align__(1024) char lds[2 * 65536 + 8192];
    float* e2s = (float*)(lds + 131072);

    const int ncc = meta[1] >> 5;
    const int tid  = threadIdx.x;
    const int w    = tid >> 6, lane = tid & 63;
    const int l15  = lane & 15, l4 = lane >> 4;
    const int wm   = w >> 1, wn = w & 1;
    const int row0 = blockIdx.x * 256;
    const int gsw  = (lane & 3) ^ ((lane >> 3) & 3);
    const int lq   = lane >> 2;
    const int rslot = (l4 ^ ((l15 >> 1) & 3)) * 16;

    f32x4 acc[4][8];
    float best[16];
    int   bidx[16];
    #pragma unroll
    for (int t = 0; t < 16; ++t) { best[t] = 3.4e38f; bidx[t] = 0; }

    auto stageA = [&](const f16* rowbase, int koff, char* unit) {
        #pragma unroll
        for (int q = 0; q < 2; ++q) {
            const int r = w * 32 + q * 16 + lq;
            gload_lds16(rowbase + (size_t)r * DIM + koff + gsw * 8,
                        unit + w * 2048 + q * 1024 + lane * 16);
        }
    };
    auto stageB = [&](int tileBase, int koff, char* unitH, char* unitL) {
        #pragma unroll
        for (int q = 0; q < 2; ++q) {
            const int r = w * 32 + q * 16 + lq;
            const int pr = cmap[tileBase + r];
            gload_lds16(eh + (size_t)pr * DIM + koff + gsw * 8,
                        unitH + w * 2048 + q * 1024 + lane * 16);
            gload_lds16(el + (size_t)pr * DIM + koff + gsw * 8,
                        unitL + w * 2048 + q * 1024 + lane * 16);
        }
    };

    ((f32x4*)e2s)[tid] = ((const f32x4*)ce2)[tid];
    stageA(xh + (size_t)row0 * DIM, 0, lds + OFF_AH);
    stageA(xl + (size_t)row0 * DIM, 0, lds + OFF_AL);
    stageB(0, 0, lds + OFF_BH, lds + OFF_BL);

    for (int cc = 0; cc < ncc; ++cc) {
        char* buf  = lds + (cc & 1) * 65536;
        char* nbuf = lds + ((cc + 1) & 1) * 65536;
        const int ct = cc >> 3, sd = cc & 7;
        const int nn = cc + 1;
        const int nct = nn >> 3, nsd = nn & 7;
        const bool more = (nn < ncc);

        if (sd == 0) {
            #pragma unroll
            for (int i = 0; i < 4; ++i)
                #pragma unroll
                for (int j = 0; j < 8; ++j)
                    acc[i][j] = (f32x4){0.f, 0.f, 0.f, 0.f};
        }

        asm volatile("s_waitcnt vmcnt(0)" ::: "memory");
        __builtin_amdgcn_s_barrier();
        __builtin_amdgcn_sched_barrier(0);

        if (more) {
            stageA(xh + (size_t)row0 * DIM, nsd * 32, nbuf + OFF_AH);
            stageA(xl + (size_t)row0 * DIM, nsd * 32, nbuf + OFF_AL);
            stageB(nct * 256, nsd * 32, nbuf + OFF_BH, nbuf + OFF_BL);
        }

        f16x8 ah[4], al[4], bh[8], bl[8];
        #pragma unroll
        for (int i = 0; i < 4; ++i)
            ah[i] = *(const f16x8*)(buf + OFF_AH + (wm * 64 + i * 16 + l15) * 64 + rslot);
        #pragma unroll
        for (int j = 0; j < 8; ++j)
            bh[j] = *(const f16x8*)(buf + OFF_BH + (wn * 128 + j * 16 + l15) * 64 + rslot);
        #pragma unroll
        for (int i = 0; i < 4; ++i)
            al[i] = *(const f16x8*)(buf + OFF_AL + (wm * 64 + i * 16 + l15) * 64 + rslot);

        #pragma unroll
        for (int i = 0; i < 4; ++i)
            #pragma unroll
            for (int j = 0; j < 8; ++j)
                acc[i][j] = MFMA16(ah[i], bh[j], acc[i][j]);
        #pragma unroll
        for (int i = 0; i < 4; ++i)
            #pragma unroll
            for (int j = 0; j < 8; ++j)
                acc[i][j] = MFMA16(al[i], bh[j], acc[i][j]);

        #pragma unroll
        for (int j = 0; j < 8; ++j)
            bl[j] = *(const f16x8*)(buf + OFF_BL + (wn * 128 + j * 16 + l15) * 64 + rslot);
        #pragma unroll
        for (int i = 0; i < 4; ++i)
            #pragma unroll
            for (int j = 0; j < 8; ++j)
                acc[i][j] = MFMA16(ah[i], bl[j], acc[i][j]);

        if (sd == 7) {
            const int cbase = ct * 256 + wn * 128;
            #pragma unroll
            for (int j = 0; j < 8; ++j) {
                const int col = cbase + j * 16 + l15;
                const float e2v = e2s[col];
                #pragma unroll
                for (int i = 0; i < 4; ++i)
                    #pragma unroll
                    for (int r = 0; r < 4; ++r) {
                        float m = fmaf(-2.0f, acc[i][j][r], e2v);
                        const int tt_ = i * 4 + r;
                        if (m < best[tt_]) { best[tt_] = m; bidx[tt_] = col; }
                    }
            }
        }
    }

    __syncthreads();
    float* rv = (float*)lds;
    int*   ri = (int*)(lds + 4096);
    #pragma unroll
    for (int tt_ = 0; tt_ < 16; ++tt_) {
        float v = best[tt_];
        int  ix = bidx[tt_];
        #pragma unroll
        for (int m = 1; m <= 8; m <<= 1) {
            float ov = __shfl_xor(v, m, 64);
            int  oix = __shfl_xor(ix, m, 64);
            if (ov < v || (ov == v && oix < ix)) { v = ov; ix = oix; }
        }
        if (l15 == 0) {
            const int rl = wm * 64 + (tt_ >> 2) * 16 + l4 * 4 + (tt_ & 3);
            rv[rl * 2 + wn] = v;
            ri[rl * 2 + wn] = ix;
        }
    }
    __syncthreads();
    if (tid < 256) {
        float v0 = rv[tid * 2], v1 = rv[tid * 2 + 1];
        int   i0 = ri[tid * 2], i1 = ri[tid * 2 + 1];
        int ibc = (v1 < v0 || (v1 == v0 && i1 < i0)) ? i1 : i0;
        int ib = cmap[ibc];
        flat_ind[row0 + tid] = ib;
        unsigned long long pending = ~0ULL;
        while (pending) {
            int leader = __ffsll((long long)pending) - 1;
            int lind = __shfl(ib, leader, 64);
            unsigned long long same = __ballot(ib == lind);
            if ((tid & 63) == leader) atomicAdd(&cnt[lind], (int)__popcll(same));
            pending &= ~same;
        }
    }
}

// ---------------------------------------------------------------------------
// scan: exclusive prefix sum over 2048 counts -> offsets, cursor
// ---------------------------------------------------------------------------
__global__ __launch_bounds__(256) void scan_kernel(
    const int* __restrict__ cnt, int* __restrict__ offs, int* __restrict__ cursor)
{
    __shared__ int ps[256];
    const int t = threadIdx.x;
    int pre[8], s = 0;
    #pragma unroll
    for (int j = 0; j < 8; ++j) { pre[j] = s; s += cnt[t * 8 + j]; }
    ps[t] = s;
    __syncthreads();
    for (int off = 1; off < 256; off <<= 1) {
        int v = (t >= off) ? ps[t - off] : 0;
        __syncthreads();
        ps[t] += v;
        __syncthreads();
    }
    int ex = (t > 0) ? ps[t - 1] : 0;
    #pragma unroll
    for (int j = 0; j < 8; ++j) {
        offs[t * 8 + j]   = ex + pre[j];
        cursor[t * 8 + j] = ex + pre[j];
    }
}

// ---------------------------------------------------------------------------
// assign: counting-sort placement with wave-aggregated cursor atomics.
// ---------------------------------------------------------------------------
__global__ __launch_bounds__(256) void assign_kernel(
    const int* __restrict__ flat_ind, int* __restrict__ cursor,
    int* __restrict__ rowlist, int* __restrict__ codesorted)
{
    const int i    = blockIdx.x * 256 + threadIdx.x;
    const int lane = threadIdx.x & 63;
    const int ind  = flat_ind[i];
    int pos = 0;
    unsigned long long pending = ~0ULL;
    while (pending) {
        int leader = __ffsll((long long)pending) - 1;
        int lind = __shfl(ind, leader, 64);
        unsigned long long same = __ballot(ind == lind);
        if (ind == lind) {
            int base = 0;
            if (lane == leader) base = atomicAdd(&cursor[lind], (int)__popcll(same));
            base = __shfl(base, leader, 64);
            pos = base + (int)__popcll(same & ((1ULL << lane) - 1ULL));
        }
        pending &= ~same;
    }
    rowlist[pos] = i;
    codesorted[pos] = ind;
}

// ---------------------------------------------------------------------------
// codesum: pure chunked segmented reduction over sorted rows (skew-proof).
// ---------------------------------------------------------------------------
__global__ __launch_bounds__(256) void codesum_kernel(
    const float* __restrict__ x, const int* __restrict__ rowlist,
    const int* __restrict__ codesorted, float* __restrict__ sums)
{
    const int p0 = blockIdx.x * 64;
    __shared__ int rows[64], codes[64];
    if (threadIdx.x < 64) {
        rows[threadIdx.x]  = rowlist[p0 + threadIdx.x];
        codes[threadIdx.x] = codesorted[p0 + threadIdx.x];
    }
    __syncthreads();
    const int d = threadIdx.x;
    float acc = 0.f;
    int cur = codes[0];
    #pragma unroll 4
    for (int r = 0; r < 64; ++r) {
        const int c = codes[r];
        if (c != cur) {
            atomicAdd(&sums[(size_t)cur * DIM + d], acc);
            acc = 0.f; cur = c;
        }
        acc += x[(size_t)rows[r] * DIM + d];
    }
    atomicAdd(&sums[(size_t)cur * DIM + d], acc);
}

// ---------------------------------------------------------------------------
// fused quantize + finalize (wide streaming)
// ---------------------------------------------------------------------------
__global__ __launch_bounds__(256) void quant_final_kernel(
    const float* __restrict__ embed, const int* __restrict__ flat_ind,
    float* __restrict__ out_q, float* __restrict__ out_ind_f, int N, int nq,
    const float* __restrict__ embed_sum, const float* __restrict__ usage,
    const float* __restrict__ sums, const int* __restrict__ cnt,
    float* __restrict__ out_usage, float* __restrict__ out_es)
{
    if ((int)blockIdx.x < nq) {
        int i = blockIdx.x * 256 + threadIdx.x;   // over N*64 float4s
        int row = i >> 6, c4 = i & 63;
        int ind = flat_ind[row];
        ((f32x4*)out_q)[i] = ((const f32x4*)embed)[ind * 64 + c4];
        if (i < N) out_ind_f[i] = (float)flat_ind[i];
    } else {
        const int k = blockIdx.x - nq, d = threadIdx.x;
        out_es[k * DIM + d] = embed_sum[k * DIM + d] * DECAYF + sums[k * DIM + d] * (1.0f - DECAYF);
        if (d == 0)
            out_usage[k] = usage[k] * DECAYF + (float)cnt[k] * (1.0f - DECAYF);
    }
}

extern "C" void kernel_launch(void* const* d_in, const int* in_sizes, int n_in,
                              void* d_out, int out_size, void* d_ws, size_t ws_size,
                              hipStream_t stream)
{
    const float* hs        = (const float*)d_in[0];
    const float* embed_sum = (const float*)d_in[1];
    const float* usage     = (const float*)d_in[2];
    const int N = in_sizes[0] / DIM;   // 65536

    float* ws_f      = (float*)d_ws;
    float* embed     = ws_f;                         // K*D f32
    float* e2        = embed + KCODES * DIM;         // K
    float* sums      = e2 + KCODES;                  // K*D f32  -- one memset covers
    int*   cnt       = (int*)(sums + KCODES * DIM);  // K           sums+cnt+pmax+pmin
    unsigned* pmax   = (unsigned*)(cnt + KCODES);    // 64  (key-encoded, init 0x00)
    unsigned* pmin   = pmax + 64;                    // 64  (key-encoded, init 0x00)
    f16*   eh        = (f16*)(pmin + 64);            // K*D f16
    f16*   el        = eh + KCODES * DIM;            // K*D f16
    float* ce2       = (float*)(el + KCODES * DIM);  // K
    int*   cmap      = (int*)(ce2 + KCODES);         // K
    int*   meta      = cmap + KCODES;                // 16
    int*   offs      = meta + 16;                    // K
    int*   cursor    = offs + KCODES;                // K
    int*   rowlist   = cursor + KCODES;              // N
    int*   codesorted= rowlist + N;                  // N
    int*   flat_ind  = codesorted + N;               // N

    float* out_q     = (float*)d_out;                // N*D
    float* out_ind   = out_q + (size_t)N * DIM;      // N
    float* out_usage = out_ind + N;                  // K
    float* out_es    = out_usage + KCODES;           // K*D

    // xh/xl live in the out_q region (exactly N*D*4B); dead after argmin,
    // quant_final overwrites out_q afterwards.
    f16* xh = (f16*)out_q;
    f16* xl = xh + (size_t)N * DIM;

    // single memset: sums + cnt + pmax + pmin (encoded keys init to 0)
    hipMemsetAsync(sums, 0, (size_t)(KCODES * DIM + KCODES + 128) * sizeof(float), stream);

    const int nsplit = N * DIM / 8 / 256;            // 8192
    split_prep_kernel<<<nsplit + KCODES, 256, 0, stream>>>(
        hs, xh, xl, nsplit, embed_sum, usage, embed, eh, el, e2, pmax, pmin);
    compactA_kernel<<<1, 256, 0, stream>>>(e2, pmax, pmin, ce2, cmap, meta);
    argmin_kernel<<<N / 256, 512, 0, stream>>>(xh, xl, eh, el, ce2, cmap, meta,
                                               flat_ind, cnt);
    scan_kernel<<<1, 256, 0, stream>>>(cnt, offs, cursor);
    assign_kernel<<<N / 256, 256, 0, stream>>>(flat_ind, cursor, rowlist, codesorted);
    codesum_kernel<<<N / 64, 256, 0, stream>>>(hs, rowlist, codesorted, sums);
    const int nq = N * DIM / 4 / 256;                // 16384
    quant_final_kernel<<<nq + KCODES, 256, 0, stream>>>(
        embed, flat_ind, out_q, out_ind, N, nq,
        embed_sum, usage, sums, cnt, out_usage, out_es);
}

// Round 12
// 267.533 us; speedup vs baseline: 1.3202x; 1.0451x over previous
//
#include <hip/hip_runtime.h>

#define EPSF 1e-5f
#define DECAYF 0.99f
#define KCODES 2048
#define DIM 256

typedef _Float16 f16;
typedef f16 f16x8 __attribute__((ext_vector_type(8)));
typedef float f32x4 __attribute__((ext_vector_type(4)));

#define MFMA16(A, B, C) __builtin_amdgcn_mfma_f32_16x16x32_f16(A, B, C, 0, 0, 0)

#define OFF_AH 0
#define OFF_AL 16384
#define OFF_BH 32768
#define OFF_BL 49152

__device__ __forceinline__ void gload_lds16(const void* g, void* l) {
    __builtin_amdgcn_global_load_lds(
        (const __attribute__((address_space(1))) void*)g,
        (__attribute__((address_space(3))) void*)l, 16, 0, 0);
}

// ---------------------------------------------------------------------------
// fused split_x + prep_embed + zero(sums,cnt); stats via 64-slot partial
// atomics (low contention). Order-preserving uint keys, both atomicMax,
// both init 0x00000000:
//   maxx2 key = u(x2) | 0x80000000 ; mine2 key = ~u(-e2)
// block ranges: [0,nsplit) split x; [nsplit,nsplit+K) prep embed;
//               [nsplit+K, nsplit+2K) zero sums/cnt (used by LATER dispatches)
// ---------------------------------------------------------------------------
__global__ __launch_bounds__(256) void split_prep_kernel(
    const float* __restrict__ x, f16* __restrict__ xh, f16* __restrict__ xl, int nsplit,
    const float* __restrict__ embed_sum, const float* __restrict__ usage,
    float* __restrict__ embed, f16* __restrict__ eh, f16* __restrict__ el,
    float* __restrict__ e2, unsigned* __restrict__ pmax, unsigned* __restrict__ pmin,
    float* __restrict__ sums, int* __restrict__ cnt)
{
    if ((int)blockIdx.x < nsplit) {
        int i = blockIdx.x * 256 + threadIdx.x;
        f32x4 v0 = ((const f32x4*)x)[2 * i];
        f32x4 v1 = ((const f32x4*)x)[2 * i + 1];
        f16x8 h, l;
        float p = 0.f;
        #pragma unroll
        for (int t = 0; t < 4; ++t) {
            f16 h0 = (f16)v0[t]; h[t] = h0; l[t] = (f16)(v0[t] - (float)h0);
            f16 h1 = (f16)v1[t]; h[t + 4] = h1; l[t + 4] = (f16)(v1[t] - (float)h1);
            p += v0[t] * v0[t] + v1[t] * v1[t];
        }
        ((f16x8*)xh)[i] = h;
        ((f16x8*)xl)[i] = l;
        #pragma unroll
        for (int m = 1; m <= 16; m <<= 1) p += __shfl_xor(p, m, 64);
        float q = fmaxf(p, __shfl_xor(p, 32, 64));
        __shared__ float wmax[4];
        if ((threadIdx.x & 63) == 0) wmax[threadIdx.x >> 6] = q;
        __syncthreads();
        if (threadIdx.x == 0) {
            float bm = fmaxf(fmaxf(wmax[0], wmax[1]), fmaxf(wmax[2], wmax[3]));
            atomicMax(&pmax[blockIdx.x & 63], __float_as_uint(bm) | 0x80000000u);
        }
    } else if ((int)blockIdx.x < nsplit + KCODES) {
        int k = blockIdx.x - nsplit;
        int d = threadIdx.x;
        float inv = 1.0f / fmaxf(usage[k], EPSF);
        float e = embed_sum[k * DIM + d] * inv;
        embed[k * DIM + d] = e;
        float ec = fminf(fmaxf(e, -65000.0f), 65000.0f);
        f16 h = (f16)ec;
        f16 l = (f16)(ec - (float)h);
        eh[k * DIM + d] = h;
        el[k * DIM + d] = l;
        float sq = e * e;
        #pragma unroll
        for (int off = 32; off > 0; off >>= 1) sq += __shfl_down(sq, off, 64);
        __shared__ float ws[4];
        if ((threadIdx.x & 63) == 0) ws[threadIdx.x >> 6] = sq;
        __syncthreads();
        if (threadIdx.x == 0) {
            float s = ws[0] + ws[1] + ws[2] + ws[3];
            e2[k] = s;
            atomicMax(&pmin[k & 63], ~__float_as_uint(-s));
        }
    } else {
        int k = blockIdx.x - nsplit - KCODES;
        sums[k * DIM + threadIdx.x] = 0.f;
        if (threadIdx.x == 0) cnt[k] = 0;
    }
}

// ---------------------------------------------------------------------------
// compactA: reduce 64-slot stats -> exact prune threshold; STABLE compaction
// (1 block). Winner bound: ||e_k|| <= 2*max||x|| + min||e||.
// ---------------------------------------------------------------------------
__global__ __launch_bounds__(256) void compactA_kernel(
    const float* __restrict__ e2, const unsigned* __restrict__ pmax,
    const unsigned* __restrict__ pmin, float* __restrict__ ce2,
    int* __restrict__ cmap, int* __restrict__ meta)
{
    __shared__ int ps[256];
    __shared__ float sT;
    const int t = threadIdx.x;
    if (t < 64) {
        unsigned km = pmax[t], kn = pmin[t];
        #pragma unroll
        for (int m = 1; m <= 32; m <<= 1) {
            km = max(km, (unsigned)__shfl_xor((int)km, m, 64));
            kn = max(kn, (unsigned)__shfl_xor((int)kn, m, 64));
        }
        if (t == 0) {
            float mx = __uint_as_float(km & 0x7FFFFFFFu);
            float mn = -__uint_as_float(~kn);
            float T0 = 2.0f * sqrtf(mx) + sqrtf(mn);
            sT = T0 * T0 * 1.0002f + 1.0f;
        }
    }
    __syncthreads();
    const float T = sT;
    int flag[8], pre[8], s = 0;
    float ev[8];
    #pragma unroll
    for (int j = 0; j < 8; ++j) {
        ev[j] = e2[t * 8 + j];
        flag[j] = (ev[j] <= T) ? 1 : 0;
        pre[j] = s; s += flag[j];
    }
    ps[t] = s;
    __syncthreads();
    for (int off = 1; off < 256; off <<= 1) {
        int v = (t >= off) ? ps[t - off] : 0;
        __syncthreads();
        ps[t] += v;
        __syncthreads();
    }
    const int ex = (t > 0) ? ps[t - 1] : 0;
    const int kp = ps[255];
    #pragma unroll
    for (int j = 0; j < 8; ++j) {
        const int k = t * 8 + j;
        if (flag[j]) {
            const int p = ex + pre[j];
            ce2[p] = ev[j];
            cmap[p] = k;
        }
    }
    for (int j = t; j < KCODES; j += 256)
        if (j >= kp) { ce2[j] = 3.4e38f; cmap[j] = 0; }
    if (t == 0) { meta[0] = kp; meta[1] = (kp + 255) & ~255; }
}

// ---------------------------------------------------------------------------
// argmin over the pruned codebook. Chunk body REORDERED: ds_reads issue
// FIRST (pinned via sched_barrier), staging issues after (its cmap-gather +
// HBM latency hides under the 96-MFMA window), so reads never wait behind
// the stage (LDS-alias conservative ordering).
// ---------------------------------------------------------------------------
__global__ __launch_bounds__(512, 2) void argmin_kernel(
    const f16* __restrict__ xh, const f16* __restrict__ xl,
    const f16* __restrict__ eh, const f16* __restrict__ el,
    const float* __restrict__ ce2, const int* __restrict__ cmap,
    const int* __restrict__ meta, int* __restrict__ flat_ind, int* __restrict__ cnt)
{
    __shared__ __align__(1024) char lds[2 * 65536 + 8192];
    float* e2s = (float*)(lds + 131072);

    const int ncc = meta[1] >> 5;
    const int tid  = threadIdx.x;
    const int w    = tid >> 6, lane = tid & 63;
    const int l15  = lane & 15, l4 = lane >> 4;
    const int wm   = w >> 1, wn = w & 1;
    const int row0 = blockIdx.x * 256;
    const int gsw  = (lane & 3) ^ ((lane >> 3) & 3);
    const int lq   = lane >> 2;
    const int rslot = (l4 ^ ((l15 >> 1) & 3)) * 16;

    f32x4 acc[4][8];
    float best[16];
    int   bidx[16];
    #pragma unroll
    for (int t = 0; t < 16; ++t) { best[t] = 3.4e38f; bidx[t] = 0; }

    auto stageA = [&](const f16* rowbase, int koff, char* unit) {
        #pragma unroll
        for (int q = 0; q < 2; ++q) {
            const int r = w * 32 + q * 16 + lq;
            gload_lds16(rowbase + (size_t)r * DIM + koff + gsw * 8,
                        unit + w * 2048 + q * 1024 + lane * 16);
        }
    };
    auto stageB = [&](int tileBase, int koff, char* unitH, char* unitL) {
        #pragma unroll
        for (int q = 0; q < 2; ++q) {
            const int r = w * 32 + q * 16 + lq;
            const int pr = cmap[tileBase + r];
            gload_lds16(eh + (size_t)pr * DIM + koff + gsw * 8,
                        unitH + w * 2048 + q * 1024 + lane * 16);
            gload_lds16(el + (size_t)pr * DIM + koff + gsw * 8,
                        unitL + w * 2048 + q * 1024 + lane * 16);
        }
    };

    ((f32x4*)e2s)[tid] = ((const f32x4*)ce2)[tid];
    stageA(xh + (size_t)row0 * DIM, 0, lds + OFF_AH);
    stageA(xl + (size_t)row0 * DIM, 0, lds + OFF_AL);
    stageB(0, 0, lds + OFF_BH, lds + OFF_BL);

    for (int cc = 0; cc < ncc; ++cc) {
        char* buf  = lds + (cc & 1) * 65536;
        char* nbuf = lds + ((cc + 1) & 1) * 65536;
        const int ct = cc >> 3, sd = cc & 7;
        const int nn = cc + 1;
        const int nct = nn >> 3, nsd = nn & 7;
        const bool more = (nn < ncc);

        if (sd == 0) {
            #pragma unroll
            for (int i = 0; i < 4; ++i)
                #pragma unroll
                for (int j = 0; j < 8; ++j)
                    acc[i][j] = (f32x4){0.f, 0.f, 0.f, 0.f};
        }

        asm volatile("s_waitcnt vmcnt(0)" ::: "memory");
        __builtin_amdgcn_s_barrier();
        __builtin_amdgcn_sched_barrier(0);

        // ---- reads FIRST: ah + bh (12 x ds_read_b128), pinned before stage
        f16x8 ah[4], al[4], bh[8], bl[8];
        #pragma unroll
        for (int i = 0; i < 4; ++i)
            ah[i] = *(const f16x8*)(buf + OFF_AH + (wm * 64 + i * 16 + l15) * 64 + rslot);
        #pragma unroll
        for (int j = 0; j < 8; ++j)
            bh[j] = *(const f16x8*)(buf + OFF_BH + (wn * 128 + j * 16 + l15) * 64 + rslot);
        __builtin_amdgcn_sched_barrier(0);

        // ---- stage next chunk (latency hides under the MFMA window below)
        if (more) {
            stageA(xh + (size_t)row0 * DIM, nsd * 32, nbuf + OFF_AH);
            stageA(xl + (size_t)row0 * DIM, nsd * 32, nbuf + OFF_AL);
            stageB(nct * 256, nsd * 32, nbuf + OFF_BH, nbuf + OFF_BL);
        }

        // ---- MFMA pass 1: ah * bh
        #pragma unroll
        for (int i = 0; i < 4; ++i)
            #pragma unroll
            for (int j = 0; j < 8; ++j)
                acc[i][j] = MFMA16(ah[i], bh[j], acc[i][j]);

        // ---- pass 2: al * bh
        #pragma unroll
        for (int i = 0; i < 4; ++i)
            al[i] = *(const f16x8*)(buf + OFF_AL + (wm * 64 + i * 16 + l15) * 64 + rslot);
        #pragma unroll
        for (int i = 0; i < 4; ++i)
            #pragma unroll
            for (int j = 0; j < 8; ++j)
                acc[i][j] = MFMA16(al[i], bh[j], acc[i][j]);

        // ---- pass 3: ah * bl
        #pragma unroll
        for (int j = 0; j < 8; ++j)
            bl[j] = *(const f16x8*)(buf + OFF_BL + (wn * 128 + j * 16 + l15) * 64 + rslot);
        #pragma unroll
        for (int i = 0; i < 4; ++i)
            #pragma unroll
            for (int j = 0; j < 8; ++j)
                acc[i][j] = MFMA16(ah[i], bl[j], acc[i][j]);

        if (sd == 7) {
            const int cbase = ct * 256 + wn * 128;
            #pragma unroll
            for (int j = 0; j < 8; ++j) {
                const int col = cbase + j * 16 + l15;
                const float e2v = e2s[col];
                #pragma unroll
                for (int i = 0; i < 4; ++i)
                    #pragma unroll
                    for (int r = 0; r < 4; ++r) {
                        float m = fmaf(-2.0f, acc[i][j][r], e2v);
                        const int tt_ = i * 4 + r;
                        if (m < best[tt_]) { best[tt_] = m; bidx[tt_] = col; }
                    }
            }
        }
    }

    __syncthreads();
    float* rv = (float*)lds;
    int*   ri = (int*)(lds + 4096);
    #pragma unroll
    for (int tt_ = 0; tt_ < 16; ++tt_) {
        float v = best[tt_];
        int  ix = bidx[tt_];
        #pragma unroll
        for (int m = 1; m <= 8; m <<= 1) {
            float ov = __shfl_xor(v, m, 64);
            int  oix = __shfl_xor(ix, m, 64);
            if (ov < v || (ov == v && oix < ix)) { v = ov; ix = oix; }
        }
        if (l15 == 0) {
            const int rl = wm * 64 + (tt_ >> 2) * 16 + l4 * 4 + (tt_ & 3);
            rv[rl * 2 + wn] = v;
            ri[rl * 2 + wn] = ix;
        }
    }
    __syncthreads();
    if (tid < 256) {
        float v0 = rv[tid * 2], v1 = rv[tid * 2 + 1];
        int   i0 = ri[tid * 2], i1 = ri[tid * 2 + 1];
        int ibc = (v1 < v0 || (v1 == v0 && i1 < i0)) ? i1 : i0;
        int ib = cmap[ibc];
        flat_ind[row0 + tid] = ib;
        unsigned long long pending = ~0ULL;
        while (pending) {
            int leader = __ffsll((long long)pending) - 1;
            int lind = __shfl(ib, leader, 64);
            unsigned long long same = __ballot(ib == lind);
            if ((tid & 63) == leader) atomicAdd(&cnt[lind], (int)__popcll(same));
            pending &= ~same;
        }
    }
}

// ---------------------------------------------------------------------------
// scan: exclusive prefix sum over 2048 counts -> offsets, cursor
// ---------------------------------------------------------------------------
__global__ __launch_bounds__(256) void scan_kernel(
    const int* __restrict__ cnt, int* __restrict__ offs, int* __restrict__ cursor)
{
    __shared__ int ps[256];
    const int t = threadIdx.x;
    int pre[8], s = 0;
    #pragma unroll
    for (int j = 0; j < 8; ++j) { pre[j] = s; s += cnt[t * 8 + j]; }
    ps[t] = s;
    __syncthreads();
    for (int off = 1; off < 256; off <<= 1) {
        int v = (t >= off) ? ps[t - off] : 0;
        __syncthreads();
        ps[t] += v;
        __syncthreads();
    }
    int ex = (t > 0) ? ps[t - 1] : 0;
    #pragma unroll
    for (int j = 0; j < 8; ++j) {
        offs[t * 8 + j]   = ex + pre[j];
        cursor[t * 8 + j] = ex + pre[j];
    }
}

// ---------------------------------------------------------------------------
// assign: counting-sort placement with wave-aggregated cursor atomics.
// ---------------------------------------------------------------------------
__global__ __launch_bounds__(256) void assign_kernel(
    const int* __restrict__ flat_ind, int* __restrict__ cursor,
    int* __restrict__ rowlist, int* __restrict__ codesorted)
{
    const int i    = blockIdx.x * 256 + threadIdx.x;
    const int lane = threadIdx.x & 63;
    const int ind  = flat_ind[i];
    int pos = 0;
    unsigned long long pending = ~0ULL;
    while (pending) {
        int leader = __ffsll((long long)pending) - 1;
        int lind = __shfl(ind, leader, 64);
        unsigned long long same = __ballot(ind == lind);
        if (ind == lind) {
            int base = 0;
            if (lane == leader) base = atomicAdd(&cursor[lind], (int)__popcll(same));
            base = __shfl(base, leader, 64);
            pos = base + (int)__popcll(same & ((1ULL << lane) - 1ULL));
        }
        pending &= ~same;
    }
    rowlist[pos] = i;
    codesorted[pos] = ind;
}

// ---------------------------------------------------------------------------
// fused codesum + quantize (independent block ranges; quantize fills the
// GPU while the 1024 codesum blocks run).
// blocks [0, nc): segmented reduction over sorted rows (skew-proof)
// blocks [nc, nc+nq): out_q = embed[flat_ind], out_ind = (float)flat_ind
// ---------------------------------------------------------------------------
__global__ __launch_bounds__(256) void codesum_quant_kernel(
    const float* __restrict__ x, const int* __restrict__ rowlist,
    const int* __restrict__ codesorted, float* __restrict__ sums, int nc,
    const float* __restrict__ embed, const int* __restrict__ flat_ind,
    float* __restrict__ out_q, float* __restrict__ out_ind_f, int N)
{
    if ((int)blockIdx.x < nc) {
        const int p0 = blockIdx.x * 64;
        __shared__ int rows[64], codes[64];
        if (threadIdx.x < 64) {
            rows[threadIdx.x]  = rowlist[p0 + threadIdx.x];
            codes[threadIdx.x] = codesorted[p0 + threadIdx.x];
        }
        __syncthreads();
        const int d = threadIdx.x;
        float acc = 0.f;
        int cur = codes[0];
        #pragma unroll 4
        for (int r = 0; r < 64; ++r) {
            const int c = codes[r];
            if (c != cur) {
                atomicAdd(&sums[(size_t)cur * DIM + d], acc);
                acc = 0.f; cur = c;
            }
            acc += x[(size_t)rows[r] * DIM + d];
        }
        atomicAdd(&sums[(size_t)cur * DIM + d], acc);
    } else {
        int i = (blockIdx.x - nc) * 256 + threadIdx.x;   // over N*64 float4s
        int row = i >> 6, c4 = i & 63;
        int ind = flat_ind[row];
        ((f32x4*)out_q)[i] = ((const f32x4*)embed)[ind * 64 + c4];
        if (i < N) out_ind_f[i] = (float)flat_ind[i];
    }
}

// ---------------------------------------------------------------------------
// finalize: EMA update outputs
// ---------------------------------------------------------------------------
__global__ __launch_bounds__(256) void finalize_kernel(
    const float* __restrict__ embed_sum, const float* __restrict__ usage,
    const float* __restrict__ sums, const int* __restrict__ cnt,
    float* __restrict__ out_usage, float* __restrict__ out_es)
{
    const int k = blockIdx.x, d = threadIdx.x;
    out_es[k * DIM + d] = embed_sum[k * DIM + d] * DECAYF + sums[k * DIM + d] * (1.0f - DECAYF);
    if (d == 0)
        out_usage[k] = usage[k] * DECAYF + (float)cnt[k] * (1.0f - DECAYF);
}

extern "C" void kernel_launch(void* const* d_in, const int* in_sizes, int n_in,
                              void* d_out, int out_size, void* d_ws, size_t ws_size,
                              hipStream_t stream)
{
    const float* hs        = (const float*)d_in[0];
    const float* embed_sum = (const float*)d_in[1];
    const float* usage     = (const float*)d_in[2];
    const int N = in_sizes[0] / DIM;   // 65536

    float* ws_f      = (float*)d_ws;
    float* embed     = ws_f;                         // K*D f32
    float* e2        = embed + KCODES * DIM;         // K
    float* sums      = e2 + KCODES;                  // K*D f32 (zeroed in split_prep)
    int*   cnt       = (int*)(sums + KCODES * DIM);  // K       (zeroed in split_prep)
    unsigned* pmax   = (unsigned*)(cnt + KCODES);    // 64  (memset 0)
    unsigned* pmin   = pmax + 64;                    // 64  (memset 0)
    f16*   eh        = (f16*)(pmin + 64);            // K*D f16
    f16*   el        = eh + KCODES * DIM;            // K*D f16
    float* ce2       = (float*)(el + KCODES * DIM);  // K
    int*   cmap      = (int*)(ce2 + KCODES);         // K
    int*   meta      = cmap + KCODES;                // 16
    int*   offs      = meta + 16;                    // K
    int*   cursor    = offs + KCODES;                // K
    int*   rowlist   = cursor + KCODES;              // N
    int*   codesorted= rowlist + N;                  // N
    int*   flat_ind  = codesorted + N;               // N

    float* out_q     = (float*)d_out;                // N*D
    float* out_ind   = out_q + (size_t)N * DIM;      // N
    float* out_usage = out_ind + N;                  // K
    float* out_es    = out_usage + KCODES;           // K*D

    // xh/xl live in the out_q region (exactly N*D*4B); dead after argmin,
    // codesum_quant overwrites out_q afterwards.
    f16* xh = (f16*)out_q;
    f16* xl = xh + (size_t)N * DIM;

    hipMemsetAsync(pmax, 0, 128 * sizeof(unsigned), stream);

    const int nsplit = N * DIM / 8 / 256;            // 8192
    split_prep_kernel<<<nsplit + 2 * KCODES, 256, 0, stream>>>(
        hs, xh, xl, nsplit, embed_sum, usage, embed, eh, el, e2, pmax, pmin,
        sums, cnt);
    compactA_kernel<<<1, 256, 0, stream>>>(e2, pmax, pmin, ce2, cmap, meta);
    argmin_kernel<<<N / 256, 512, 0, stream>>>(xh, xl, eh, el, ce2, cmap, meta,
                                               flat_ind, cnt);
    scan_kernel<<<1, 256, 0, stream>>>(cnt, offs, cursor);
    assign_kernel<<<N / 256, 256, 0, stream>>>(flat_ind, cursor, rowlist, codesorted);
    const int nc = N / 64;                           // 1024
    const int nq = N * DIM / 4 / 256;                // 16384
    codesum_quant_kernel<<<nc + nq, 256, 0, stream>>>(
        hs, rowlist, codesorted, sums, nc, embed, flat_ind, out_q, out_ind, N);
    finalize_kernel<<<KCODES, 256, 0, stream>>>(embed_sum, usage, sums, cnt,
                                                out_usage, out_es);
}